// Round 12
// baseline (52.826 us; speedup 1.0000x reference)
//
#include <hip/hip_runtime.h>

// Shapes fixed by setup_inputs(): B=4, L=1024, A=5, KNN=32, K=16.
// Output: [B, L, KNN, A*A*K] f32 = 209.7 MB — write-bound (fill floor ~31us).
// R1: 64B/thread stores 69us. R2: coalesced f32x4 48.1. R4: +nt 46.2.
// R5-R9: geometry sweep under nt — flat 46-54 (confounded). R10: drop nt
//     -> 41.7 (nt bypassed L2 write-combining, cost 4.5us). R11: 8 f4/thr
//     -> 41.0; depth ladder converged. ~5.1 TB/s vs 6.8 blit.
// R12: discriminate "load-instruction pressure" vs "at the floor": 2-kernel
//     split, plain stores. A: all scattered gathers once per (edge,pair)
//     -> x[q] ws (13.1 MB, coalesced). B: R11 store structure, only 2 load
//     instrs/wave-iter (x 4-lane-shared + att). VMEM instrs 13 -> 3.
constexpr int A_DIM   = 5;
constexpr int PAIRS   = 25;    // A*A
constexpr int KNN     = 32;
constexpr int L_DIM   = 1024;
constexpr int B_DIM   = 4;
constexpr int N_EDGES = B_DIM * L_DIM * KNN;        // 131,072
constexpr int N_Q     = N_EDGES * PAIRS;            // 3,276,800
constexpr int TOTAL_F4 = N_Q * 4;                   // 13,107,200 f32x4
constexpr int F4_PER_THREAD = 8;
constexpr int F4_PER_BLOCK  = 256 * F4_PER_THREAD;  // 2048
// 1/sqrt(2*3.1415926)  (reference uses pi literal 3.1415926)
constexpr float INV_SQRT_2PI = 0.39894228f;

typedef float f32x4 __attribute__((ext_vector_type(4)));

// ---- Phase A: one thread per (edge,pair); every scattered gather ONCE ----
__global__ __launch_bounds__(256) void edge_x_kernel(
    const float* __restrict__ X,           // [B,L,A,3]
    const int*   __restrict__ E_idx,       // [B,L,KNN]
    const float* __restrict__ mask_atoms,  // [B,L,A]
    const float* __restrict__ mul,         // [25]
    const float* __restrict__ bias,        // [25]
    float*       __restrict__ xw)          // [N_Q] masked affine distances
{
    const unsigned q    = blockIdx.x * 256u + threadIdx.x;
    const unsigned e    = q / PAIRS;                 // magic-mul
    const int      pair = (int)(q - e * PAIRS);
    const int      i    = pair / A_DIM;              // neighbor atom
    const int      j    = pair - i * A_DIM;          // center atom

    const unsigned bl = e >> 5;                      // b*L + l  (KNN=32)
    const unsigned b  = bl >> 10;                    // L=1024
    const int      n  = E_idx[e];
    const unsigned bn = (b << 10) | (unsigned)n;

    const float* xn = X + ((size_t)bn * A_DIM + i) * 3;
    const float* xc = X + ((size_t)bl * A_DIM + j) * 3;
    const float dx = xn[0] - xc[0];
    const float dy = xn[1] - xc[1];
    const float dz = xn[2] - xc[2];
    const float D  = sqrtf(dx * dx + dy * dy + dz * dz);

    // both masks gathered at the NEIGHBOR residue (per reference)
    const float mi = mask_atoms[(size_t)bn * A_DIM + i];
    const float mj = mask_atoms[(size_t)bn * A_DIM + j];

    // coalesced 4 B/lane store (256 B per wave-quarter, contiguous)
    xw[q] = (mul[pair] * D + bias[pair]) * (mi * mj);
}

// ---- Phase B: near-pure stream: 2 load instrs + 1 store per wave-iter ----
__global__ __launch_bounds__(256) void rbf_write_kernel(
    const float* __restrict__ xw,           // [N_Q] from phase A (LLC-hot)
    const float* __restrict__ mask_attend,  // [B,L,KNN]
    const float* __restrict__ means,        // [16]
    const float* __restrict__ stds,         // [16]
    f32x4*       __restrict__ out4)         // 13,107,200 f32x4s
{
    const int tid = threadIdx.x;
    const int c   = tid & 3;               // channel quartet, loop-invariant

    // per-thread channel constants (4 broadcast lines, once per 8 iters)
    f32x4 mu4, iv4, co4;
#pragma unroll
    for (int t = 0; t < 4; ++t) {
        const int   k   = c * 4 + t;
        const float sd  = fabsf(stds[k]) + 0.01f;
        const float inv = __builtin_amdgcn_rcpf(sd);   // ~1 ulp; thr 3.3e-2
        mu4[t] = means[k];
        iv4[t] = inv;
        co4[t] = inv * INV_SQRT_2PI;
    }

    const unsigned fbase = blockIdx.x * (unsigned)F4_PER_BLOCK + (unsigned)tid;

#pragma unroll
    for (int u = 0; u < F4_PER_THREAD; ++u) {
        const unsigned fidx = fbase + 256u * u;   // f32x4 index
        const unsigned q    = fidx >> 2;          // 16 consec q per wave-iter
        const unsigned e    = q / PAIRS;          // magic-mul (for att only)

        const float x   = xw[q];                  // 1 instr, 64B/wave, LLC-hot
        const float att = mask_attend[e];         // 1 instr, 1-2 lines

        const float z0 = (x - mu4.x) * iv4.x;
        const float z1 = (x - mu4.y) * iv4.y;
        const float z2 = (x - mu4.z) * iv4.z;
        const float z3 = (x - mu4.w) * iv4.w;
        f32x4 o;
        o.x = (co4.x * att) * __expf(-0.5f * z0 * z0);
        o.y = (co4.y * att) * __expf(-0.5f * z1 * z1);
        o.z = (co4.z * att) * __expf(-0.5f * z2 * z2);
        o.w = (co4.w * att) * __expf(-0.5f * z3 * z3);

        // plain lane-contiguous 1 KB wave-store through L2 write-combine
        out4[fidx] = o;
    }
}

extern "C" void kernel_launch(void* const* d_in, const int* in_sizes, int n_in,
                              void* d_out, int out_size, void* d_ws, size_t ws_size,
                              hipStream_t stream) {
    const float* X           = (const float*)d_in[0];
    const int*   E_idx       = (const int*)  d_in[1];
    const float* mask_atoms  = (const float*)d_in[2];
    const float* mask_attend = (const float*)d_in[3];
    const float* means       = (const float*)d_in[4];
    const float* stds        = (const float*)d_in[5];
    const float* mul         = (const float*)d_in[6];
    const float* bias        = (const float*)d_in[7];
    float*       xw          = (float*)d_ws;         // 13.1 MB (proven fits)
    f32x4*       out4        = (f32x4*)d_out;

    edge_x_kernel<<<N_Q / 256, 256, 0, stream>>>(
        X, E_idx, mask_atoms, mul, bias, xw);

    rbf_write_kernel<<<TOTAL_F4 / F4_PER_BLOCK, 256, 0, stream>>>(
        xw, mask_attend, means, stds, out4);
}

// Round 13
// 42.234 us; speedup vs baseline: 1.2508x; 1.2508x over previous
//
#include <hip/hip_runtime.h>

// Shapes fixed by setup_inputs(): B=4, L=1024, A=5, KNN=32, K=16.
// Output: [B, L, KNN, A*A*K] f32 = 209.7 MB — write-bound (fill floor ~31us).
// Ledger: R1 69 -> R2 48.1 (coalesced f32x4) -> R10 41.7 (drop nt) ->
// R11 41.0 (8 f4/thread, best). Falsified: store geometry (R7-R9), nt (R10),
// depth >8 (R11 flat), load elimination (R5/R6/R12 ALL regress — split adds
// ~5us/kernel overhead, phase-B gains nothing).
// R13: last variable — workgroup size. Same kernel as R11, block 1024,
// grid 1600. Isolates dispatch/block-churn granularity.
constexpr int A_DIM   = 5;
constexpr int PAIRS   = 25;    // A*A
constexpr int KNN     = 32;
constexpr int L_DIM   = 1024;
constexpr int B_DIM   = 4;
constexpr int N_EDGES = B_DIM * L_DIM * KNN;        // 131,072
constexpr int TOTAL_F4 = N_EDGES * PAIRS * 4;       // 13,107,200 f32x4
constexpr int BLOCK   = 1024;
constexpr int F4_PER_THREAD = 8;
constexpr int F4_PER_BLOCK  = BLOCK * F4_PER_THREAD;  // 8192
// 1/sqrt(2*3.1415926)  (reference uses pi literal 3.1415926)
constexpr float INV_SQRT_2PI = 0.39894228f;

typedef float f32x4 __attribute__((ext_vector_type(4)));

__global__ __launch_bounds__(BLOCK) void gauss_rbf_kernel(
    const float* __restrict__ X,           // [B,L,A,3]
    const int*   __restrict__ E_idx,       // [B,L,KNN]
    const float* __restrict__ mask_atoms,  // [B,L,A]
    const float* __restrict__ mask_attend, // [B,L,KNN]
    const float* __restrict__ means,       // [16]
    const float* __restrict__ stds,        // [16]
    const float* __restrict__ mul,         // [25]
    const float* __restrict__ bias,        // [25]
    f32x4*       __restrict__ out4)        // 13,107,200 f32x4s
{
    const int tid = threadIdx.x;
    const int c   = tid & 3;               // channel quartet, loop-invariant

    // per-thread channel constants (4 broadcast lines, once per 8 iters)
    f32x4 mu4, iv4, co4;
#pragma unroll
    for (int t = 0; t < 4; ++t) {
        const int   k   = c * 4 + t;
        const float sd  = fabsf(stds[k]) + 0.01f;
        const float inv = __builtin_amdgcn_rcpf(sd);   // ~1 ulp; thr 3.3e-2
        mu4[t] = means[k];
        iv4[t] = inv;
        co4[t] = inv * INV_SQRT_2PI;
    }

    const unsigned fbase = blockIdx.x * (unsigned)F4_PER_BLOCK + (unsigned)tid;

#pragma unroll
    for (int u = 0; u < F4_PER_THREAD; ++u) {
        const unsigned fidx = fbase + (unsigned)BLOCK * u;  // f32x4 index
        const unsigned q    = fidx >> 2;          // 16 consec q per wave-iter
        const unsigned e    = q / PAIRS;          // magic-mul
        const int      pair = (int)(q - e * PAIRS);
        const int      i    = pair / A_DIM;       // neighbor atom
        const int      j    = pair - i * A_DIM;   // center atom

        const unsigned bl = e >> 5;               // b*L + l  (KNN=32)
        const unsigned b  = bl >> 10;             // L=1024
        const int      n  = E_idx[e];
        const unsigned bn = (b << 10) | (unsigned)n;

        // L1/L2-resident gathers; a wave-iter touches 1-2 edges
        const float* xn = X + ((size_t)bn * A_DIM + i) * 3;
        const float* xc = X + ((size_t)bl * A_DIM + j) * 3;
        const float dx = xn[0] - xc[0];
        const float dy = xn[1] - xc[1];
        const float dz = xn[2] - xc[2];
        const float D  = sqrtf(dx * dx + dy * dy + dz * dz);

        // both masks gathered at the NEIGHBOR residue (per reference)
        const float mi = mask_atoms[(size_t)bn * A_DIM + i];
        const float mj = mask_atoms[(size_t)bn * A_DIM + j];

        const float x   = (mul[pair] * D + bias[pair]) * (mi * mj);
        const float att = mask_attend[e];

        const float z0 = (x - mu4.x) * iv4.x;
        const float z1 = (x - mu4.y) * iv4.y;
        const float z2 = (x - mu4.z) * iv4.z;
        const float z3 = (x - mu4.w) * iv4.w;
        f32x4 o;
        o.x = (co4.x * att) * __expf(-0.5f * z0 * z0);
        o.y = (co4.y * att) * __expf(-0.5f * z1 * z1);
        o.z = (co4.z * att) * __expf(-0.5f * z2 * z2);
        o.w = (co4.w * att) * __expf(-0.5f * z3 * z3);

        // plain lane-contiguous 1 KB wave-store through L2 write-combine
        out4[fidx] = o;
    }
}

extern "C" void kernel_launch(void* const* d_in, const int* in_sizes, int n_in,
                              void* d_out, int out_size, void* d_ws, size_t ws_size,
                              hipStream_t stream) {
    const float* X           = (const float*)d_in[0];
    const int*   E_idx       = (const int*)  d_in[1];
    const float* mask_atoms  = (const float*)d_in[2];
    const float* mask_attend = (const float*)d_in[3];
    const float* means       = (const float*)d_in[4];
    const float* stds        = (const float*)d_in[5];
    const float* mul         = (const float*)d_in[6];
    const float* bias        = (const float*)d_in[7];
    f32x4*       out4        = (f32x4*)d_out;

    const int grid = TOTAL_F4 / F4_PER_BLOCK;   // 1,600 blocks (exact)

    gauss_rbf_kernel<<<grid, BLOCK, 0, stream>>>(
        X, E_idx, mask_atoms, mask_attend, means, stds, mul, bias, out4);
}